// Round 1
// baseline (987.733 us; speedup 1.0000x reference)
//
#include <hip/hip_runtime.h>
#include <stdint.h>

// Problem constants (fixed by the reference)
constexpr int NN = 131072;          // coarse nodes
constexpr int EE = 1048576;         // edges
constexpr int NF = 4 * NN;          // fine nodes = 524288
constexpr int KK = 3 * NF;          // unpool entries = 1572864
constexpr int CS = 64;              // C_SKIP
constexpr int CC = 128;             // 2*C_SKIP
constexpr int CO = 64;              // C_OUT

// ---------------------------------------------------------------------------
// 1) Transpose x = [a;b] (128 x N channel-major) -> xT (N x 128 node-major)
// ---------------------------------------------------------------------------
__global__ __launch_bounds__(256) void k_transpose(
    const float* __restrict__ a, const float* __restrict__ b,
    float* __restrict__ xT)
{
    __shared__ float tile[128][33];
    int i0 = blockIdx.x * 32;
    for (int f = threadIdx.x; f < 128 * 32; f += 256) {
        int c = f >> 5, j = f & 31;
        const float* src = (c < 64) ? a : b;
        tile[c][j] = src[(size_t)(c & 63) * NN + i0 + j];
    }
    __syncthreads();
    for (int f = threadIdx.x; f < 128 * 32; f += 256) {
        int c = f & 127, j = f >> 7;
        xT[(size_t)(i0 + j) * CC + c] = tile[c][j];
    }
}

// ---------------------------------------------------------------------------
// 2) Counting-sort machinery: histogram, 2-level exclusive scan, scatter
// ---------------------------------------------------------------------------
__global__ __launch_bounds__(256) void k_hist(
    const int* __restrict__ idx, int M, int* __restrict__ cnt)
{
    int e = blockIdx.x * 256 + threadIdx.x;
    if (e < M) atomicAdd(&cnt[idx[e]], 1);
}

// block totals over 1024-element chunks
__global__ __launch_bounds__(256) void k_scan_bsum(
    const int* __restrict__ cnt, int nb, int* __restrict__ bsum)
{
    __shared__ int s[256];
    int base = blockIdx.x * 1024;
    int sum = 0;
    for (int j = threadIdx.x; j < 1024; j += 256) {
        int g = base + j;
        sum += (g < nb) ? cnt[g] : 0;
    }
    s[threadIdx.x] = sum;
    __syncthreads();
    for (int o = 128; o > 0; o >>= 1) {
        if (threadIdx.x < o) s[threadIdx.x] += s[threadIdx.x + o];
        __syncthreads();
    }
    if (threadIdx.x == 0) bsum[blockIdx.x] = s[0];
}

// single-block exclusive scan of up to 512 block sums
__global__ __launch_bounds__(512) void k_scan_exc(int* __restrict__ bsum, int nblk)
{
    __shared__ int s[512];
    int t = threadIdx.x;
    s[t] = (t < nblk) ? bsum[t] : 0;
    __syncthreads();
    for (int o = 1; o < 512; o <<= 1) {
        int v = (t >= o) ? s[t - o] : 0;
        __syncthreads();
        s[t] += v;
        __syncthreads();
    }
    if (t < nblk) bsum[t] = (t == 0) ? 0 : s[t - 1];
}

// final offsets (exclusive) + cursor init; also writes offs[nb] = total
__global__ __launch_bounds__(256) void k_scan_final(
    const int* __restrict__ cnt, int nb, const int* __restrict__ bsum,
    int* __restrict__ offs, int* __restrict__ curs)
{
    __shared__ int ts[256];
    int base = blockIdx.x * 1024;
    int loc[4];
    int sum = 0;
    for (int u = 0; u < 4; ++u) {
        int g = base + threadIdx.x * 4 + u;
        int v = (g < nb) ? cnt[g] : 0;
        loc[u] = sum;
        sum += v;
    }
    ts[threadIdx.x] = sum;
    __syncthreads();
    for (int o = 1; o < 256; o <<= 1) {
        int v = (threadIdx.x >= o) ? ts[threadIdx.x - o] : 0;
        __syncthreads();
        ts[threadIdx.x] += v;
        __syncthreads();
    }
    int texc = (threadIdx.x == 0) ? 0 : ts[threadIdx.x - 1];
    int bb = bsum[blockIdx.x];
    for (int u = 0; u < 4; ++u) {
        int g = base + threadIdx.x * 4 + u;
        if (g < nb) {
            int o = bb + texc + loc[u];
            offs[g] = o;
            curs[g] = o;
        }
    }
    if (blockIdx.x == gridDim.x - 1 && threadIdx.x == 255)
        offs[nb] = bb + ts[255];
}

__global__ __launch_bounds__(256) void k_scatter(
    const int* __restrict__ bucket, const int* __restrict__ payload, int M,
    int* __restrict__ curs, int* __restrict__ out)
{
    int e = blockIdx.x * 256 + threadIdx.x;
    if (e < M) {
        int p = atomicAdd(&curs[bucket[e]], 1);
        out[p] = payload[e];
    }
}

// ---------------------------------------------------------------------------
// 3) Fused pull-aggregation + GEMM + bias + relu -> hT (N x 64 node-major)
//    One wave per node. W matrices in LDS, k-major, XOR-swizzled:
//    W[c][k] stored at lw[m][k*64 + (c ^ ((k>>1)&31))]
//    -> conflict-free staging writes, free 2-way compute reads.
// ---------------------------------------------------------------------------
__global__ __launch_bounds__(256) void k_agg_h(
    const float2* __restrict__ xT2, const int* __restrict__ offsE,
    const int* __restrict__ sortedG,
    const float* __restrict__ Wself, const float* __restrict__ Wneigh,
    const float* __restrict__ bias, float* __restrict__ hT)
{
    __shared__ float lw[2][128 * 64];   // exactly 64 KiB
    for (int f = threadIdx.x; f < 64 * 128; f += 256) {
        int c = f >> 7, k = f & 127;
        int d = (k << 6) + (c ^ ((k >> 1) & 31));
        lw[0][d] = Wself[f];
        lw[1][d] = Wneigh[f];
    }
    float bias_c = bias[threadIdx.x & 63];
    __syncthreads();

    int w = threadIdx.x >> 6, lane = threadIdx.x & 63;
    for (int it = 0; it < 16; ++it) {
        int i = (blockIdx.x << 6) + (it << 2) + w;
        int beg = offsE[i], end = offsE[i + 1];

        // pull-aggregate: lane holds features {2*lane, 2*lane+1}
        float2 agg = make_float2(0.f, 0.f);
        for (int p0 = beg; p0 < end; p0 += 64) {
            int nn = min(64, end - p0);
            int g = (lane < nn) ? sortedG[p0 + lane] : 0;
            int q = 0;
            for (; q + 3 < nn; q += 4) {  // 4 loads in flight
                int g0 = __shfl(g, q), g1 = __shfl(g, q + 1);
                int g2 = __shfl(g, q + 2), g3 = __shfl(g, q + 3);
                float2 v0 = xT2[(size_t)g0 * 64 + lane];
                float2 v1 = xT2[(size_t)g1 * 64 + lane];
                float2 v2 = xT2[(size_t)g2 * 64 + lane];
                float2 v3 = xT2[(size_t)g3 * 64 + lane];
                agg.x += v0.x + v1.x + v2.x + v3.x;
                agg.y += v0.y + v1.y + v2.y + v3.y;
            }
            for (; q < nn; ++q) {
                int gq = __shfl(g, q);
                float2 v = xT2[(size_t)gq * 64 + lane];
                agg.x += v.x;
                agg.y += v.y;
            }
        }

        float2 xv = xT2[(size_t)i * 64 + lane];

        // h[c] = relu(bias[c] + sum_k Wself[c][k]*x[k] + Wneigh[c][k]*agg[k])
        float hacc = bias_c;
#pragma unroll 8
        for (int m = 0; m < 64; ++m) {
            float xk0 = __shfl(xv.x, m), xk1 = __shfl(xv.y, m);
            float ak0 = __shfl(agg.x, m), ak1 = __shfl(agg.y, m);
            int base = (m << 7) + (lane ^ (m & 31));
            hacc += lw[0][base] * xk0 + lw[0][base + 64] * xk1
                  + lw[1][base] * ak0 + lw[1][base + 64] * ak1;
        }
        hT[(size_t)i * 64 + lane] = fmaxf(hacc, 0.f);
    }
}

// ---------------------------------------------------------------------------
// 4) Pull unpool scatter-max: block owns 64 fine nodes; coalesced write-once
// ---------------------------------------------------------------------------
__global__ __launch_bounds__(256) void k_unpool(
    const float* __restrict__ hT, const int* __restrict__ offsU,
    const int* __restrict__ sortedS, float* __restrict__ out)
{
    __shared__ float buf[64][65];
    int j0 = blockIdx.x * 64;
    int w = threadIdx.x >> 6, lane = threadIdx.x & 63;
    for (int jj = w; jj < 64; jj += 4) {
        int j = j0 + jj;
        int beg = offsU[j], end = offsU[j + 1];
        float m = 0.f;
        for (int p0 = beg; p0 < end; p0 += 64) {
            int nn = min(64, end - p0);
            int s = (lane < nn) ? sortedS[p0 + lane] : 0;
            int q = 0;
            for (; q + 3 < nn; q += 4) {
                int s0 = __shfl(s, q), s1 = __shfl(s, q + 1);
                int s2 = __shfl(s, q + 2), s3 = __shfl(s, q + 3);
                float v0 = hT[(size_t)s0 * 64 + lane];
                float v1 = hT[(size_t)s1 * 64 + lane];
                float v2 = hT[(size_t)s2 * 64 + lane];
                float v3 = hT[(size_t)s3 * 64 + lane];
                m = fmaxf(m, fmaxf(fmaxf(v0, v1), fmaxf(v2, v3)));
            }
            for (; q < nn; ++q) {
                int sq = __shfl(s, q);
                m = fmaxf(m, hT[(size_t)sq * 64 + lane]);
            }
        }
        buf[jj][lane] = m;
    }
    __syncthreads();
    for (int f = threadIdx.x; f < 64 * 64; f += 256) {
        int c = f >> 6, j = f & 63;
        out[(size_t)c * NF + j0 + j] = buf[j][c];
    }
}

// ---------------------------------------------------------------------------
extern "C" void kernel_launch(void* const* d_in, const int* in_sizes, int n_in,
                              void* d_out, int out_size, void* d_ws, size_t ws_size,
                              hipStream_t stream)
{
    const float* a      = (const float*)d_in[0];
    const float* b      = (const float*)d_in[1];
    const float* Wself  = (const float*)d_in[2];
    const float* Wneigh = (const float*)d_in[3];
    const float* bias   = (const float*)d_in[4];
    const int* gather_i = (const int*)d_in[5];
    const int* reduce_i = (const int*)d_in[6];
    const int* up_src   = (const int*)d_in[7];
    const int* up_dst   = (const int*)d_in[8];
    float* out = (float*)d_out;

    // workspace layout (all 4-byte elems)
    float* xT      = (float*)d_ws;                       // N*128
    float* hT      = xT + (size_t)NN * CC;               // N*64
    int*   sortedG = (int*)(hT + (size_t)NN * CO);       // E
    int*   sortedS = sortedG + EE;                       // K
    int*   cntE    = sortedS + KK;                       // N
    int*   offsE   = cntE + NN;                          // N+1
    int*   cursE   = offsE + NN + 1;                     // N
    int*   cntU    = cursE + NN;                         // NF
    int*   offsU   = cntU + NF;                          // NF+1
    int*   cursU   = offsU + NF + 1;                     // NF
    int*   bsum    = cursU + NF;                         // 1024

    size_t need = ((size_t)NN * CC + (size_t)NN * CO + EE + KK +
                   3 * (size_t)NN + 1 + 3 * (size_t)NF + 1 + 1024) * 4;
    if (ws_size < need) return;  // fail visibly (output stays poisoned)

    // 1) transpose
    k_transpose<<<NN / 32, 256, 0, stream>>>(a, b, xT);

    // 2) histograms
    hipMemsetAsync(cntE, 0, (size_t)NN * 4, stream);
    hipMemsetAsync(cntU, 0, (size_t)NF * 4, stream);
    k_hist<<<EE / 256, 256, 0, stream>>>(reduce_i, EE, cntE);
    k_hist<<<KK / 256, 256, 0, stream>>>(up_dst, KK, cntU);

    // 3) scans (edges: 128 chunks; unpool: 512 chunks)
    k_scan_bsum<<<NN / 1024, 256, 0, stream>>>(cntE, NN, bsum);
    k_scan_exc<<<1, 512, 0, stream>>>(bsum, NN / 1024);
    k_scan_final<<<NN / 1024, 256, 0, stream>>>(cntE, NN, bsum, offsE, cursE);

    k_scan_bsum<<<NF / 1024, 256, 0, stream>>>(cntU, NF, bsum);
    k_scan_exc<<<1, 512, 0, stream>>>(bsum, NF / 1024);
    k_scan_final<<<NF / 1024, 256, 0, stream>>>(cntU, NF, bsum, offsU, cursU);

    // 4) bucket scatter (CSR adjacency lists)
    k_scatter<<<EE / 256, 256, 0, stream>>>(reduce_i, gather_i, EE, cursE, sortedG);
    k_scatter<<<KK / 256, 256, 0, stream>>>(up_dst, up_src, KK, cursU, sortedS);

    // 5) fused aggregation + GEMM + relu
    k_agg_h<<<NN / 64, 256, 0, stream>>>((const float2*)xT, offsE, sortedG,
                                         Wself, Wneigh, bias, hT);

    // 6) pull unpool (writes every output element exactly once)
    k_unpool<<<NF / 64, 256, 0, stream>>>(hT, offsU, sortedS, out);
}

// Round 3
// 517.576 us; speedup vs baseline: 1.9084x; 1.9084x over previous
//
#include <hip/hip_runtime.h>
#include <stdint.h>

// Problem constants (fixed by the reference)
constexpr int NN = 131072;          // coarse nodes
constexpr int EE = 1048576;         // edges
constexpr int NF = 4 * NN;          // fine nodes = 524288
constexpr int KK = 3 * NF;          // unpool entries = 1572864

typedef __attribute__((ext_vector_type(8))) short bf16x8;
typedef __attribute__((ext_vector_type(4))) float f32x4;

__device__ inline uint32_t bf16rn(float f) {
    uint32_t u = __float_as_uint(f);
    return (u + 0x7FFFu + ((u >> 16) & 1u)) >> 16;
}
__device__ inline uint32_t pack2(float lo, float hi) {
    return bf16rn(lo) | (bf16rn(hi) << 16);
}
__device__ inline float bf_lo(uint32_t v) { return __uint_as_float(v << 16); }
__device__ inline float bf_hi(uint32_t v) { return __uint_as_float(v & 0xFFFF0000u); }

// ---------------------------------------------------------------------------
// 1) Transpose x = [a;b] (128 x N, f32) -> xTb (N x 128, bf16, node-major)
//    packed as N x 64 u32 (features {2p,2p+1} per u32)
// ---------------------------------------------------------------------------
__global__ __launch_bounds__(256) void k_transpose(
    const float* __restrict__ a, const float* __restrict__ b,
    uint32_t* __restrict__ xTb)
{
    __shared__ float tile[128][33];
    int i0 = blockIdx.x * 32;
    for (int f = threadIdx.x; f < 128 * 32; f += 256) {
        int c = f >> 5, j = f & 31;
        const float* src = (c < 64) ? a : b;
        tile[c][j] = src[(size_t)(c & 63) * NN + i0 + j];
    }
    __syncthreads();
    for (int f = threadIdx.x; f < 64 * 32; f += 256) {
        int p = f & 63, j = f >> 6;
        xTb[(size_t)(i0 + j) * 64 + p] = pack2(tile[2 * p][j], tile[2 * p + 1][j]);
    }
}

// ---------------------------------------------------------------------------
// 2) Counting-sort machinery: histogram, 2-level exclusive scan, scatter
// ---------------------------------------------------------------------------
__global__ __launch_bounds__(256) void k_hist(
    const int* __restrict__ idx, int M, int* __restrict__ cnt)
{
    int e = blockIdx.x * 256 + threadIdx.x;
    if (e < M) atomicAdd(&cnt[idx[e]], 1);
}

__global__ __launch_bounds__(256) void k_scan_bsum(
    const int* __restrict__ cnt, int nb, int* __restrict__ bsum)
{
    __shared__ int s[256];
    int base = blockIdx.x * 1024;
    int sum = 0;
    for (int j = threadIdx.x; j < 1024; j += 256) {
        int g = base + j;
        sum += (g < nb) ? cnt[g] : 0;
    }
    s[threadIdx.x] = sum;
    __syncthreads();
    for (int o = 128; o > 0; o >>= 1) {
        if (threadIdx.x < o) s[threadIdx.x] += s[threadIdx.x + o];
        __syncthreads();
    }
    if (threadIdx.x == 0) bsum[blockIdx.x] = s[0];
}

__global__ __launch_bounds__(512) void k_scan_exc(int* __restrict__ bsum, int nblk)
{
    __shared__ int s[512];
    int t = threadIdx.x;
    s[t] = (t < nblk) ? bsum[t] : 0;
    __syncthreads();
    for (int o = 1; o < 512; o <<= 1) {
        int v = (t >= o) ? s[t - o] : 0;
        __syncthreads();
        s[t] += v;
        __syncthreads();
    }
    if (t < nblk) bsum[t] = (t == 0) ? 0 : s[t - 1];
}

__global__ __launch_bounds__(256) void k_scan_final(
    const int* __restrict__ cnt, int nb, const int* __restrict__ bsum,
    int* __restrict__ offs, int* __restrict__ curs)
{
    __shared__ int ts[256];
    int base = blockIdx.x * 1024;
    int loc[4];
    int sum = 0;
    for (int u = 0; u < 4; ++u) {
        int g = base + threadIdx.x * 4 + u;
        int v = (g < nb) ? cnt[g] : 0;
        loc[u] = sum;
        sum += v;
    }
    ts[threadIdx.x] = sum;
    __syncthreads();
    for (int o = 1; o < 256; o <<= 1) {
        int v = (threadIdx.x >= o) ? ts[threadIdx.x - o] : 0;
        __syncthreads();
        ts[threadIdx.x] += v;
        __syncthreads();
    }
    int texc = (threadIdx.x == 0) ? 0 : ts[threadIdx.x - 1];
    int bb = bsum[blockIdx.x];
    for (int u = 0; u < 4; ++u) {
        int g = base + threadIdx.x * 4 + u;
        if (g < nb) {
            int o = bb + texc + loc[u];
            offs[g] = o;
            curs[g] = o;
        }
    }
    if (blockIdx.x == gridDim.x - 1 && threadIdx.x == 255)
        offs[nb] = bb + ts[255];
}

__global__ __launch_bounds__(256) void k_scatter(
    const int* __restrict__ bucket, const int* __restrict__ payload, int M,
    int* __restrict__ curs, int* __restrict__ out)
{
    int e = blockIdx.x * 256 + threadIdx.x;
    if (e < M) {
        int p = atomicAdd(&curs[bucket[e]], 1);
        out[p] = payload[e];
    }
}

// ---------------------------------------------------------------------------
// 3) Pure pull-aggregation: wave per node, lane = feature-pair (u32 of 2 bf16)
//    No LDS -> full occupancy for latency hiding. f32 accumulate, bf16 out.
// ---------------------------------------------------------------------------
__global__ __launch_bounds__(256) void k_agg(
    const uint32_t* __restrict__ xTb, const int* __restrict__ offsE,
    const int* __restrict__ sortedG, uint32_t* __restrict__ aggB)
{
    int w = threadIdx.x >> 6, lane = threadIdx.x & 63;
    int i = blockIdx.x * 4 + w;
    int beg = offsE[i], end = offsE[i + 1];
    float sx = 0.f, sy = 0.f;
    for (int p0 = beg; p0 < end; p0 += 64) {
        int nn = min(64, end - p0);
        int g = (lane < nn) ? sortedG[p0 + lane] : 0;
        int q = 0;
        for (; q + 3 < nn; q += 4) {
            int g0 = __shfl(g, q), g1 = __shfl(g, q + 1);
            int g2 = __shfl(g, q + 2), g3 = __shfl(g, q + 3);
            uint32_t v0 = xTb[(size_t)g0 * 64 + lane];
            uint32_t v1 = xTb[(size_t)g1 * 64 + lane];
            uint32_t v2 = xTb[(size_t)g2 * 64 + lane];
            uint32_t v3 = xTb[(size_t)g3 * 64 + lane];
            sx += bf_lo(v0) + bf_lo(v1) + bf_lo(v2) + bf_lo(v3);
            sy += bf_hi(v0) + bf_hi(v1) + bf_hi(v2) + bf_hi(v3);
        }
        for (; q < nn; ++q) {
            int gq = __shfl(g, q);
            uint32_t v = xTb[(size_t)gq * 64 + lane];
            sx += bf_lo(v);
            sy += bf_hi(v);
        }
    }
    aggB[(size_t)i * 64 + lane] = pack2(sx, sy);
}

// ---------------------------------------------------------------------------
// 4) MFMA GEMM: h = relu([Wself|Wneigh] @ [x;agg] + bias), bf16 in, bf16 out.
//    No LDS. Wave handles 16 nodes/group. A-frag: lane holds W[mt*16+(l&15)]
//    [k=kt*32+(l>>4)*8 ..+8]; B-frag: lane holds feat row of node g*16+(l&15),
//    same k slice -> both are direct 16 B row-major loads.
//    C/D: col(node)=l&15, row(c)=(l>>4)*4+r  [m89-verified layout]
// ---------------------------------------------------------------------------
__global__ __launch_bounds__(256) void k_gemm(
    const uint32_t* __restrict__ xTb, const uint32_t* __restrict__ aggB,
    const float* __restrict__ Wself, const float* __restrict__ Wneigh,
    const float* __restrict__ bias, uint32_t* __restrict__ hT)
{
    int lane = threadIdx.x & 63;
    int wid = blockIdx.x * 4 + (threadIdx.x >> 6);
    int lr = lane & 15, lq = lane >> 4;

    // W fragments in VGPRs (reused across all groups)
    bf16x8 wf[4][8];
#pragma unroll
    for (int mt = 0; mt < 4; ++mt) {
#pragma unroll
        for (int kt = 0; kt < 8; ++kt) {
            const float* W = (kt < 4) ? Wself : Wneigh;
            const float* p = W + (size_t)(mt * 16 + lr) * 128 + (kt & 3) * 32 + lq * 8;
            bf16x8 v;
#pragma unroll
            for (int j = 0; j < 8; ++j) v[j] = (short)bf16rn(p[j]);
            wf[mt][kt] = v;
        }
    }
    float bv[4][4];
#pragma unroll
    for (int mt = 0; mt < 4; ++mt)
#pragma unroll
        for (int r = 0; r < 4; ++r)
            bv[mt][r] = bias[mt * 16 + lq * 4 + r];

    const int NG = NN / 16;
    int stride = gridDim.x * 4;
    for (int g = wid; g < NG; g += stride) {
        int n = g * 16 + lr;
        const uint32_t* xr = xTb + (size_t)n * 64 + lq * 4;
        const uint32_t* ar = aggB + (size_t)n * 64 + lq * 4;
        bf16x8 bq[8];
#pragma unroll
        for (int kt = 0; kt < 4; ++kt)
            bq[kt] = *reinterpret_cast<const bf16x8*>(xr + kt * 16);
#pragma unroll
        for (int kt = 0; kt < 4; ++kt)
            bq[4 + kt] = *reinterpret_cast<const bf16x8*>(ar + kt * 16);
#pragma unroll
        for (int mt = 0; mt < 4; ++mt) {
            f32x4 acc = {0.f, 0.f, 0.f, 0.f};
#pragma unroll
            for (int kt = 0; kt < 8; ++kt)
                acc = __builtin_amdgcn_mfma_f32_16x16x32_bf16(wf[mt][kt], bq[kt], acc, 0, 0, 0);
            uint32_t u0 = pack2(fmaxf(acc[0] + bv[mt][0], 0.f), fmaxf(acc[1] + bv[mt][1], 0.f));
            uint32_t u1 = pack2(fmaxf(acc[2] + bv[mt][2], 0.f), fmaxf(acc[3] + bv[mt][3], 0.f));
            *reinterpret_cast<uint2*>(hT + (size_t)n * 32 + mt * 8 + lq * 2) = make_uint2(u0, u1);
        }
    }
}

// ---------------------------------------------------------------------------
// 5) Pull unpool scatter-max on bf16 hT. Post-relu values are >= 0, so bf16
//    bit-pattern max == numeric max. Lane = channel (ushort loads).
// ---------------------------------------------------------------------------
__global__ __launch_bounds__(256) void k_unpool(
    const uint16_t* __restrict__ hT, const int* __restrict__ offsU,
    const int* __restrict__ sortedS, float* __restrict__ out)
{
    __shared__ uint16_t buf[64][65];
    int j0 = blockIdx.x * 64;
    int w = threadIdx.x >> 6, lane = threadIdx.x & 63;
    for (int jj = w; jj < 64; jj += 4) {
        int beg = offsU[j0 + jj], end = offsU[j0 + jj + 1];
        uint32_t m = 0;
        for (int p0 = beg; p0 < end; p0 += 64) {
            int nn = min(64, end - p0);
            int s = (lane < nn) ? sortedS[p0 + lane] : 0;
            int q = 0;
            for (; q + 3 < nn; q += 4) {
                int s0 = __shfl(s, q), s1 = __shfl(s, q + 1);
                int s2 = __shfl(s, q + 2), s3 = __shfl(s, q + 3);
                uint32_t v0 = hT[(size_t)s0 * 64 + lane];
                uint32_t v1 = hT[(size_t)s1 * 64 + lane];
                uint32_t v2 = hT[(size_t)s2 * 64 + lane];
                uint32_t v3 = hT[(size_t)s3 * 64 + lane];
                m = max(m, max(max(v0, v1), max(v2, v3)));
            }
            for (; q < nn; ++q) {
                int sq = __shfl(s, q);
                m = max(m, (uint32_t)hT[(size_t)sq * 64 + lane]);
            }
        }
        buf[jj][lane] = (uint16_t)m;
    }
    __syncthreads();
    for (int f = threadIdx.x; f < 64 * 64; f += 256) {
        int c = f >> 6, j = f & 63;
        out[(size_t)c * NF + j0 + j] = __uint_as_float(((uint32_t)buf[j][c]) << 16);
    }
}

// ---------------------------------------------------------------------------
extern "C" void kernel_launch(void* const* d_in, const int* in_sizes, int n_in,
                              void* d_out, int out_size, void* d_ws, size_t ws_size,
                              hipStream_t stream)
{
    const float* a      = (const float*)d_in[0];
    const float* b      = (const float*)d_in[1];
    const float* Wself  = (const float*)d_in[2];
    const float* Wneigh = (const float*)d_in[3];
    const float* bias   = (const float*)d_in[4];
    const int* gather_i = (const int*)d_in[5];
    const int* reduce_i = (const int*)d_in[6];
    const int* up_src   = (const int*)d_in[7];
    const int* up_dst   = (const int*)d_in[8];
    float* out = (float*)d_out;

    // workspace layout (all 4-byte elems)
    uint32_t* xTb  = (uint32_t*)d_ws;                    // N*64 (bf16 pairs)
    uint32_t* aggB = xTb + (size_t)NN * 64;              // N*64
    uint32_t* hT   = aggB + (size_t)NN * 64;             // N*32 (bf16 pairs)
    int* sortedG   = (int*)(hT + (size_t)NN * 32);       // E
    int* sortedS   = sortedG + EE;                       // K
    int* cntE      = sortedS + KK;                       // N
    int* offsE     = cntE + NN;                          // N+1
    int* cursE     = offsE + NN + 1;                     // N
    int* cntU      = cursE + NN;                         // NF
    int* offsU     = cntU + NF;                          // NF+1
    int* cursU     = offsU + NF + 1;                     // NF
    int* bsum      = cursU + NF;                         // 1024

    size_t need = ((size_t)NN * 160 + EE + KK +
                   3 * (size_t)NN + 1 + 3 * (size_t)NF + 1 + 1024) * 4;
    if (ws_size < need) return;  // fail visibly (output stays poisoned)

    // 1) transpose + bf16 pack
    k_transpose<<<NN / 32, 256, 0, stream>>>(a, b, xTb);

    // 2) histograms
    (void)hipMemsetAsync(cntE, 0, (size_t)NN * 4, stream);
    (void)hipMemsetAsync(cntU, 0, (size_t)NF * 4, stream);
    k_hist<<<EE / 256, 256, 0, stream>>>(reduce_i, EE, cntE);
    k_hist<<<KK / 256, 256, 0, stream>>>(up_dst, KK, cntU);

    // 3) scans
    k_scan_bsum<<<NN / 1024, 256, 0, stream>>>(cntE, NN, bsum);
    k_scan_exc<<<1, 512, 0, stream>>>(bsum, NN / 1024);
    k_scan_final<<<NN / 1024, 256, 0, stream>>>(cntE, NN, bsum, offsE, cursE);

    k_scan_bsum<<<NF / 1024, 256, 0, stream>>>(cntU, NF, bsum);
    k_scan_exc<<<1, 512, 0, stream>>>(bsum, NF / 1024);
    k_scan_final<<<NF / 1024, 256, 0, stream>>>(cntU, NF, bsum, offsU, cursU);

    // 4) CSR scatter
    k_scatter<<<EE / 256, 256, 0, stream>>>(reduce_i, gather_i, EE, cursE, sortedG);
    k_scatter<<<KK / 256, 256, 0, stream>>>(up_dst, up_src, KK, cursU, sortedS);

    // 5) aggregation (latency-bound gather, full occupancy)
    k_agg<<<NN / 4, 256, 0, stream>>>(xTb, offsE, sortedG, aggB);

    // 6) MFMA GEMM + bias + relu -> hT (bf16)
    k_gemm<<<512, 256, 0, stream>>>(xTb, aggB, Wself, Wneigh, bias, hT);

    // 7) pull unpool (writes every output element exactly once)
    k_unpool<<<NF / 64, 256, 0, stream>>>((const uint16_t*)hT, offsU, sortedS, out);
}